// Round 1
// baseline (1453.235 us; speedup 1.0000x reference)
//
#include <hip/hip_runtime.h>
#include <cstddef>

#define NPB 4096   // points per batch
#define KNB 20     // neighbors
#define NB  8      // batches

__device__ __forceinline__ float rlf(float v, int lane) {
    return __int_as_float(__builtin_amdgcn_readlane(__float_as_int(v), lane));
}

// ---------------------------------------------------------------------------
// Kernel B: exact top-20 (largest of dist = 2*inner - xx_n - xx_m) per point.
// One thread per point; batch tile (x,y,z,xx) staged in LDS as float4.
// Arithmetic mirrors numpy fp32 (no FMA, sequential c order) so near-tie
// selection matches the reference; strict '>' keeps lower index on ties.
// ---------------------------------------------------------------------------
__global__ __launch_bounds__(64) void knn_kernel(const float* __restrict__ x,
                                                 int* __restrict__ knn) {
    __shared__ float4 xs[NPB];            // 64 KB
    const int tid = threadIdx.x;
    const int g   = blockIdx.x * 64 + tid;
    const int b   = g >> 12;

    const float* xb = x + (size_t)b * 3 * NPB;
    for (int i = tid; i < NPB; i += 64) {
        float a0 = xb[i];
        float a1 = xb[NPB + i];
        float a2 = xb[2 * NPB + i];
        float xx = __fadd_rn(__fadd_rn(__fmul_rn(a0, a0), __fmul_rn(a1, a1)),
                             __fmul_rn(a2, a2));
        xs[i] = make_float4(a0, a1, a2, xx);
    }
    __syncthreads();

    const int n = g & (NPB - 1);
    float4 me = xs[n];
    const float cx = me.x, cy = me.y, cz = me.z, xxn = me.w;

    float vals[KNB];
    int   idxs[KNB];
#pragma unroll
    for (int j = 0; j < KNB; ++j) { vals[j] = -INFINITY; idxs[j] = 0; }
    float vmin = -INFINITY;

#pragma unroll 4
    for (int m = 0; m < NPB; ++m) {
        float4 q = xs[m];
        float inner = __fadd_rn(__fadd_rn(__fmul_rn(cx, q.x), __fmul_rn(cy, q.y)),
                                __fmul_rn(cz, q.z));
        float d = __fsub_rn(__fsub_rn(__fmul_rn(2.0f, inner), xxn), q.w);
        if (d > vmin) {
            float cv = d; int ci = m;
#pragma unroll
            for (int j = 0; j < KNB; ++j) {
                bool gt = cv > vals[j];
                float tv = vals[j]; int ti = idxs[j];
                vals[j] = gt ? cv : tv;  idxs[j] = gt ? ci : ti;
                cv      = gt ? tv : cv;  ci      = gt ? ti : ci;
            }
            vmin = vals[KNB - 1];
        }
    }

    int* kout = knn + (size_t)g * KNB;
#pragma unroll
    for (int j = 0; j < KNB; ++j) kout[j] = idxs[j];
}

// ---------------------------------------------------------------------------
// Kernel C: fused gather + conv1(6->64)+BN+ReLU + max/mean pool over K +
// conv2(128->64)+BN+ReLU. Wave-per-point (lane = output channel), 64 points
// per block (4 waves x 16 points). Outputs staged via LDS for coalesced
// 256B row writes into [B,64,N] layout sections of d_out.
// ---------------------------------------------------------------------------
__global__ __launch_bounds__(256) void fuse_kernel(
    const float* __restrict__ x, const int* __restrict__ knn,
    const float* __restrict__ w1, const float* __restrict__ b1,
    const float* __restrict__ g1, const float* __restrict__ be1,
    const float* __restrict__ rm1, const float* __restrict__ rv1,
    const float* __restrict__ w2, const float* __restrict__ b2,
    const float* __restrict__ g2, const float* __restrict__ be2,
    const float* __restrict__ rm2, const float* __restrict__ rv2,
    float* __restrict__ out)
{
    __shared__ float w2s[64 * 129];       // +1 pad -> 2-way bank alias (free)
    __shared__ float buf[64 * 65];        // output staging, padded
    __shared__ float cent[3][64];         // this block's 64 center points

    const int tid  = threadIdx.x;
    const int wave = tid >> 6;
    const int lane = tid & 63;
    const int g0   = blockIdx.x * 64;
    const int b    = g0 >> 12;
    const int n0   = g0 & (NPB - 1);

    for (int i = tid; i < 64 * 128; i += 256) {
        int o = i >> 7, c = i & 127;
        w2s[o * 129 + c] = w2[i];
    }
    for (int i = tid; i < 192; i += 256) {
        int c = i >> 6, p = i & 63;
        cent[c][p] = x[((size_t)b * 3 + c) * NPB + n0 + p];
    }
    __syncthreads();

    const int o = lane;
    const float w10 = w1[o*6+0], w11 = w1[o*6+1], w12 = w1[o*6+2];
    const float w13 = w1[o*6+3], w14 = w1[o*6+4], w15 = w1[o*6+5];
    const float sc1 = g1[o] * rsqrtf(rv1[o] + 1e-5f);
    const float sh1 = be1[o] - rm1[o] * sc1;
    const float b1o = b1[o];
    const float sc2 = g2[o] * rsqrtf(rv2[o] + 1e-5f);
    const float sh2 = be2[o] - rm2[o] * sc2;
    const float b2o = b2[o];

    // gather roles: lane l<60 fetches coord c=l%3 of neighbor k=l/3
    const int gk  = lane / 3;
    const int gc  = lane - gk * 3;
    const int gks = (gk > 19) ? 0 : gk;

    float m1r[16], m2r[16], o2r[16];

    for (int j = 0; j < 16; ++j) {
        const int pl = wave * 16 + j;
        const int gp = g0 + pl;
        int myk = (lane < KNB) ? knn[(size_t)gp * KNB + lane] : 0;
        int nk  = __shfl(myk, gks);
        float coord = x[((size_t)b * 3 + gc) * NPB + nk];
        float dif   = __fsub_rn(coord, cent[gc][pl]);

        float c0 = cent[0][pl], c1 = cent[1][pl], c2 = cent[2][pl];
        float base = b1o + c0 * w13 + c1 * w14 + c2 * w15;

        float m1 = -INFINITY, sum = 0.0f;
#pragma unroll
        for (int k = 0; k < KNB; ++k) {
            float d0 = rlf(dif, 3 * k + 0);
            float d1 = rlf(dif, 3 * k + 1);
            float d2 = rlf(dif, 3 * k + 2);
            float h  = fmaf(d2, w12, fmaf(d1, w11, fmaf(d0, w10, base)));
            float r  = fmaxf(0.0f, fmaf(h, sc1, sh1));
            m1  = fmaxf(m1, r);
            sum += r;
        }
        m1r[j] = m1;
        m2r[j] = sum / 20.0f;
    }

    // conv2: c-outer so w2s is read once per c (not once per point)
#pragma unroll
    for (int j = 0; j < 16; ++j) o2r[j] = b2o;
    for (int c = 0; c < 64; ++c) {
        float wa = w2s[o * 129 + c];
        float wb = w2s[o * 129 + 64 + c];
#pragma unroll
        for (int j = 0; j < 16; ++j) {
            o2r[j] = fmaf(rlf(m1r[j], c), wa, o2r[j]);
            o2r[j] = fmaf(rlf(m2r[j], c), wb, o2r[j]);
        }
    }
#pragma unroll
    for (int j = 0; j < 16; ++j)
        o2r[j] = fmaxf(0.0f, fmaf(o2r[j], sc2, sh2));

    const size_t SEC = (size_t)NB * 64 * NPB;   // 2,097,152 elements / section

    // section 1: m1o
#pragma unroll
    for (int j = 0; j < 16; ++j) buf[o * 65 + wave * 16 + j] = m1r[j];
    __syncthreads();
    {
        float* dst = out + SEC;
        for (int r = 0; r < 16; ++r) {
            int oo = r * 4 + wave;
            dst[((size_t)b * 64 + oo) * NPB + n0 + lane] = buf[oo * 65 + lane];
        }
    }
    __syncthreads();

    // section 2: m2o
#pragma unroll
    for (int j = 0; j < 16; ++j) buf[o * 65 + wave * 16 + j] = m2r[j];
    __syncthreads();
    {
        float* dst = out + 2 * SEC;
        for (int r = 0; r < 16; ++r) {
            int oo = r * 4 + wave;
            dst[((size_t)b * 64 + oo) * NPB + n0 + lane] = buf[oo * 65 + lane];
        }
    }
    __syncthreads();

    // section 0: out
#pragma unroll
    for (int j = 0; j < 16; ++j) buf[o * 65 + wave * 16 + j] = o2r[j];
    __syncthreads();
    {
        float* dst = out;
        for (int r = 0; r < 16; ++r) {
            int oo = r * 4 + wave;
            dst[((size_t)b * 64 + oo) * NPB + n0 + lane] = buf[oo * 65 + lane];
        }
    }
}

extern "C" void kernel_launch(void* const* d_in, const int* in_sizes, int n_in,
                              void* d_out, int out_size, void* d_ws, size_t ws_size,
                              hipStream_t stream) {
    const float* x   = (const float*)d_in[0];
    const float* w1  = (const float*)d_in[1];
    const float* b1  = (const float*)d_in[2];
    const float* g1  = (const float*)d_in[3];
    const float* be1 = (const float*)d_in[4];
    const float* rm1 = (const float*)d_in[5];
    const float* rv1 = (const float*)d_in[6];
    const float* w2  = (const float*)d_in[7];
    const float* b2  = (const float*)d_in[8];
    const float* g2  = (const float*)d_in[9];
    const float* be2 = (const float*)d_in[10];
    const float* rm2 = (const float*)d_in[11];
    const float* rv2 = (const float*)d_in[12];

    int* knn = (int*)d_ws;   // 8*4096*20*4 = 2.62 MB

    knn_kernel<<<(NB * NPB) / 64, 64, 0, stream>>>(x, knn);
    fuse_kernel<<<(NB * NPB) / 64, 256, 0, stream>>>(
        x, knn, w1, b1, g1, be1, rm1, rv1, w2, b2, g2, be2, rm2, rv2,
        (float*)d_out);
}

// Round 2
// 629.324 us; speedup vs baseline: 2.3092x; 2.3092x over previous
//
#include <hip/hip_runtime.h>
#include <cstddef>

#define NPB 4096   // points per batch
#define KNB 20     // neighbors
#define NB  8      // batches
#define BUF 16     // per-lane candidate buffer capacity (flush threshold)
#define BUFP 17    // padded stride (17*2 dwords -> 2-way bank alias, free)

__device__ __forceinline__ float rlf(float v, int lane) {
    return __int_as_float(__builtin_amdgcn_readlane(__float_as_int(v), lane));
}

// ---------------------------------------------------------------------------
// Kernel B: exact top-20 (largest of dist = 2*inner - xx_n - xx_m) per point.
// One thread per point. Candidate tile staged in LDS (2 x 2048 float4 halves).
// Passing candidates are buffered per-lane in LDS and batch-inserted into the
// register top-20 only when some lane's buffer fills -- all lanes then insert
// concurrently, amortizing the serial 20-step shift chain across the wave.
// Distance arithmetic mirrors numpy fp32 (no FMA, sequential order); strict
// '>' everywhere keeps lower index on ties (matches jax.lax.top_k).
// ---------------------------------------------------------------------------
__global__ __launch_bounds__(64) void knn_kernel(const float* __restrict__ x,
                                                 int* __restrict__ knn) {
    __shared__ float4 xs[2048];            // 32 KB half-tile
    __shared__ float2 bufs[64 * BUFP];     // 8.5 KB per-lane candidate buffers

    const int tid = threadIdx.x;
    const int g   = blockIdx.x * 64 + tid;
    const int b   = g >> 12;
    const int n   = g & (NPB - 1);
    const float* xb = x + (size_t)b * 3 * NPB;

    // my point (coalesced across the block)
    const float cx = xb[n], cy = xb[NPB + n], cz = xb[2 * NPB + n];
    const float xxn = __fadd_rn(__fadd_rn(__fmul_rn(cx, cx), __fmul_rn(cy, cy)),
                                __fmul_rn(cz, cz));

    float vals[KNB];
    int   idxs[KNB];
#pragma unroll
    for (int j = 0; j < KNB; ++j) { vals[j] = -INFINITY; idxs[j] = 0; }
    float vmin = -INFINITY;
    int   cnt  = 0;
    float2* mybuf = bufs + tid * BUFP;

    // batch-insert everything currently buffered (all lanes concurrently)
    auto flush = [&]() {
#pragma unroll
        for (int j = 0; j < BUF; ++j) {
            bool act = (j < cnt);
            if (!__any(act)) break;
            float2 e = mybuf[j];
            float cv = act ? e.x : -INFINITY;      // -inf = guaranteed no-op
            int   ci = __float_as_int(e.y);
            if (__any(cv > vmin)) {
#pragma unroll
                for (int jj = 0; jj < KNB; ++jj) {
                    bool gt = cv > vals[jj];
                    float tv = vals[jj]; int ti = idxs[jj];
                    vals[jj] = gt ? cv : tv;  idxs[jj] = gt ? ci : ti;
                    cv       = gt ? tv : cv;  ci      = gt ? ti : ci;
                }
                vmin = vals[KNB - 1];
            }
        }
        cnt = 0;
    };

#pragma unroll 1
    for (int half = 0; half < 2; ++half) {
        __syncthreads();
        const int base = half * 2048;
        for (int i = tid; i < 2048; i += 64) {
            const int m = base + i;
            float a0 = xb[m];
            float a1 = xb[NPB + m];
            float a2 = xb[2 * NPB + m];
            float xx = __fadd_rn(__fadd_rn(__fmul_rn(a0, a0), __fmul_rn(a1, a1)),
                                 __fmul_rn(a2, a2));
            xs[i] = make_float4(a0, a1, a2, xx);
        }
        __syncthreads();

#pragma unroll 4
        for (int i = 0; i < 2048; ++i) {
            float4 q = xs[i];
            float inner = __fadd_rn(__fadd_rn(__fmul_rn(cx, q.x), __fmul_rn(cy, q.y)),
                                    __fmul_rn(cz, q.z));
            float d = __fsub_rn(__fsub_rn(__fmul_rn(2.0f, inner), xxn), q.w);
            if (d > vmin) {                         // cheap predicated push
                mybuf[cnt] = make_float2(d, __int_as_float(base + i));
                ++cnt;
            }
            if (__any(cnt >= BUF)) flush();
        }
    }
    flush();                                        // leftovers

    int* kout = knn + (size_t)g * KNB;
#pragma unroll
    for (int j = 0; j < KNB; ++j) kout[j] = idxs[j];
}

// ---------------------------------------------------------------------------
// Kernel C: fused gather + conv1(6->64)+BN+ReLU + max/mean pool over K +
// conv2(128->64)+BN+ReLU. Wave-per-point (lane = output channel), 64 points
// per block (4 waves x 16 points). Outputs staged via LDS for coalesced
// 256B row writes into [B,64,N] layout sections of d_out.
// ---------------------------------------------------------------------------
__global__ __launch_bounds__(256) void fuse_kernel(
    const float* __restrict__ x, const int* __restrict__ knn,
    const float* __restrict__ w1, const float* __restrict__ b1,
    const float* __restrict__ g1, const float* __restrict__ be1,
    const float* __restrict__ rm1, const float* __restrict__ rv1,
    const float* __restrict__ w2, const float* __restrict__ b2,
    const float* __restrict__ g2, const float* __restrict__ be2,
    const float* __restrict__ rm2, const float* __restrict__ rv2,
    float* __restrict__ out)
{
    __shared__ float w2s[64 * 129];       // +1 pad -> 2-way bank alias (free)
    __shared__ float buf[64 * 65];        // output staging, padded
    __shared__ float cent[3][64];         // this block's 64 center points

    const int tid  = threadIdx.x;
    const int wave = tid >> 6;
    const int lane = tid & 63;
    const int g0   = blockIdx.x * 64;
    const int b    = g0 >> 12;
    const int n0   = g0 & (NPB - 1);

    for (int i = tid; i < 64 * 128; i += 256) {
        int o = i >> 7, c = i & 127;
        w2s[o * 129 + c] = w2[i];
    }
    for (int i = tid; i < 192; i += 256) {
        int c = i >> 6, p = i & 63;
        cent[c][p] = x[((size_t)b * 3 + c) * NPB + n0 + p];
    }
    __syncthreads();

    const int o = lane;
    const float w10 = w1[o*6+0], w11 = w1[o*6+1], w12 = w1[o*6+2];
    const float w13 = w1[o*6+3], w14 = w1[o*6+4], w15 = w1[o*6+5];
    const float sc1 = g1[o] * rsqrtf(rv1[o] + 1e-5f);
    const float sh1 = be1[o] - rm1[o] * sc1;
    const float b1o = b1[o];
    const float sc2 = g2[o] * rsqrtf(rv2[o] + 1e-5f);
    const float sh2 = be2[o] - rm2[o] * sc2;
    const float b2o = b2[o];

    // gather roles: lane l<60 fetches coord c=l%3 of neighbor k=l/3
    const int gk  = lane / 3;
    const int gc  = lane - gk * 3;
    const int gks = (gk > 19) ? 0 : gk;

    float m1r[16], m2r[16], o2r[16];

    for (int j = 0; j < 16; ++j) {
        const int pl = wave * 16 + j;
        const int gp = g0 + pl;
        int myk = (lane < KNB) ? knn[(size_t)gp * KNB + lane] : 0;
        int nk  = __shfl(myk, gks);
        float coord = x[((size_t)b * 3 + gc) * NPB + nk];
        float dif   = __fsub_rn(coord, cent[gc][pl]);

        float c0 = cent[0][pl], c1 = cent[1][pl], c2 = cent[2][pl];
        float base = b1o + c0 * w13 + c1 * w14 + c2 * w15;

        float m1 = -INFINITY, sum = 0.0f;
#pragma unroll
        for (int k = 0; k < KNB; ++k) {
            float d0 = rlf(dif, 3 * k + 0);
            float d1 = rlf(dif, 3 * k + 1);
            float d2 = rlf(dif, 3 * k + 2);
            float h  = fmaf(d2, w12, fmaf(d1, w11, fmaf(d0, w10, base)));
            float r  = fmaxf(0.0f, fmaf(h, sc1, sh1));
            m1  = fmaxf(m1, r);
            sum += r;
        }
        m1r[j] = m1;
        m2r[j] = sum / 20.0f;
    }

    // conv2: c-outer so w2s is read once per c (not once per point)
#pragma unroll
    for (int j = 0; j < 16; ++j) o2r[j] = b2o;
    for (int c = 0; c < 64; ++c) {
        float wa = w2s[o * 129 + c];
        float wb = w2s[o * 129 + 64 + c];
#pragma unroll
        for (int j = 0; j < 16; ++j) {
            o2r[j] = fmaf(rlf(m1r[j], c), wa, o2r[j]);
            o2r[j] = fmaf(rlf(m2r[j], c), wb, o2r[j]);
        }
    }
#pragma unroll
    for (int j = 0; j < 16; ++j)
        o2r[j] = fmaxf(0.0f, fmaf(o2r[j], sc2, sh2));

    const size_t SEC = (size_t)NB * 64 * NPB;   // 2,097,152 elements / section

    // section 1: m1o
#pragma unroll
    for (int j = 0; j < 16; ++j) buf[o * 65 + wave * 16 + j] = m1r[j];
    __syncthreads();
    {
        float* dst = out + SEC;
        for (int r = 0; r < 16; ++r) {
            int oo = r * 4 + wave;
            dst[((size_t)b * 64 + oo) * NPB + n0 + lane] = buf[oo * 65 + lane];
        }
    }
    __syncthreads();

    // section 2: m2o
#pragma unroll
    for (int j = 0; j < 16; ++j) buf[o * 65 + wave * 16 + j] = m2r[j];
    __syncthreads();
    {
        float* dst = out + 2 * SEC;
        for (int r = 0; r < 16; ++r) {
            int oo = r * 4 + wave;
            dst[((size_t)b * 64 + oo) * NPB + n0 + lane] = buf[oo * 65 + lane];
        }
    }
    __syncthreads();

    // section 0: out
#pragma unroll
    for (int j = 0; j < 16; ++j) buf[o * 65 + wave * 16 + j] = o2r[j];
    __syncthreads();
    {
        float* dst = out;
        for (int r = 0; r < 16; ++r) {
            int oo = r * 4 + wave;
            dst[((size_t)b * 64 + oo) * NPB + n0 + lane] = buf[oo * 65 + lane];
        }
    }
}

extern "C" void kernel_launch(void* const* d_in, const int* in_sizes, int n_in,
                              void* d_out, int out_size, void* d_ws, size_t ws_size,
                              hipStream_t stream) {
    const float* x   = (const float*)d_in[0];
    const float* w1  = (const float*)d_in[1];
    const float* b1  = (const float*)d_in[2];
    const float* g1  = (const float*)d_in[3];
    const float* be1 = (const float*)d_in[4];
    const float* rm1 = (const float*)d_in[5];
    const float* rv1 = (const float*)d_in[6];
    const float* w2  = (const float*)d_in[7];
    const float* b2  = (const float*)d_in[8];
    const float* g2  = (const float*)d_in[9];
    const float* be2 = (const float*)d_in[10];
    const float* rm2 = (const float*)d_in[11];
    const float* rv2 = (const float*)d_in[12];

    int* knn = (int*)d_ws;   // 8*4096*20*4 = 2.62 MB

    knn_kernel<<<(NB * NPB) / 64, 64, 0, stream>>>(x, knn);
    fuse_kernel<<<(NB * NPB) / 64, 256, 0, stream>>>(
        x, knn, w1, b1, g1, be1, rm1, rv1, w2, b2, g2, be2, rm2, rv2,
        (float*)d_out);
}

// Round 3
// 379.981 us; speedup vs baseline: 3.8245x; 1.6562x over previous
//
#include <hip/hip_runtime.h>
#include <cstddef>

#define NPB 4096   // points per batch
#define KNB 20     // neighbors
#define NB  8      // batches
#define BUF 16     // per-lane candidate buffer capacity (flush threshold)
#define BUFP 17    // padded stride in float2
#define SEGSZ 1024 // candidates per segment (4 segments)

__device__ __forceinline__ float rlf(float v, int lane) {
    return __int_as_float(__builtin_amdgcn_readlane(__float_as_int(v), lane));
}

// ---------------------------------------------------------------------------
// Kernel A: pack (x,y,z,xx) per point into float4 (512 KB, L2-resident).
// xx arithmetic identical to reference numpy fp32 (no FMA, sequential order).
// ---------------------------------------------------------------------------
__global__ __launch_bounds__(256) void pack_kernel(const float* __restrict__ x,
                                                   float4* __restrict__ xp) {
    const int g = blockIdx.x * 256 + threadIdx.x;      // 32768 points
    const int b = g >> 12, n = g & (NPB - 1);
    const float* xb = x + (size_t)b * 3 * NPB;
    float a0 = xb[n], a1 = xb[NPB + n], a2 = xb[2 * NPB + n];
    float xx = __fadd_rn(__fadd_rn(__fmul_rn(a0, a0), __fmul_rn(a1, a1)),
                         __fmul_rn(a2, a2));
    xp[g] = make_float4(a0, a1, a2, xx);
}

// ---------------------------------------------------------------------------
// Kernel B: exact top-20 of dist = 2*inner - xx_n - xx_m, segmented.
// Block = 256 thr = 64 points x 4 segments; wave = one segment, lane = point.
// All lanes of a wave scan the same candidate stream (wave-uniform packed
// float4 load, 1 txn/iter). Buffered batch-insert amortizes the serial
// 20-step shift across lanes. Partial sorted top-20s merged 4-way per point;
// strict '>' + lowest-segment-first = global lower-index tie preference
// (matches jax.lax.top_k).
// ---------------------------------------------------------------------------
__global__ __launch_bounds__(256) void knn_kernel(const float4* __restrict__ xp,
                                                  int* __restrict__ knn) {
    __shared__ float2 smem[64 * 81];   // 41.5 KB union: scan bufs (256*17) / merge lists (64*81)

    const int tid  = threadIdx.x;
    const int wave = tid >> 6;          // segment
    const int lane = tid & 63;          // point offset
    const int g0   = blockIdx.x * 64;
    const int b    = g0 >> 12;
    const int n0   = g0 & (NPB - 1);

    const float4 me = xp[(b << 12) + n0 + lane];       // coalesced
    const float cx = me.x, cy = me.y, cz = me.z, xxn = me.w;

    float vals[KNB];
    int   idxs[KNB];
#pragma unroll
    for (int j = 0; j < KNB; ++j) { vals[j] = -INFINITY; idxs[j] = 0; }
    float vmin = -INFINITY;
    int   cnt  = 0;
    float2* mybuf = smem + tid * BUFP;

    auto flush = [&]() {
#pragma unroll
        for (int j = 0; j < BUF; ++j) {
            bool act = (j < cnt);
            if (!__any(act)) break;
            float2 e = mybuf[j];
            float cv = act ? e.x : -INFINITY;
            int   ci = __float_as_int(e.y);
            if (__any(cv > vmin)) {
#pragma unroll
                for (int jj = 0; jj < KNB; ++jj) {
                    bool gt = cv > vals[jj];
                    float tv = vals[jj]; int ti = idxs[jj];
                    vals[jj] = gt ? cv : tv;  idxs[jj] = gt ? ci : ti;
                    cv       = gt ? tv : cv;  ci       = gt ? ti : ci;
                }
                vmin = vals[KNB - 1];
            }
        }
        cnt = 0;
    };

    const float4* cand  = xp + (b << 12) + wave * SEGSZ;
    const int     ibase = wave * SEGSZ;
#pragma unroll 4
    for (int i = 0; i < SEGSZ; ++i) {
        float4 q = cand[i];                             // wave-uniform 16B load
        float inner = __fadd_rn(__fadd_rn(__fmul_rn(cx, q.x), __fmul_rn(cy, q.y)),
                                __fmul_rn(cz, q.z));
        float d = __fsub_rn(__fsub_rn(__fmul_rn(2.0f, inner), xxn), q.w);
        if (d > vmin) {
            mybuf[cnt] = make_float2(d, __int_as_float(ibase + i));
            ++cnt;
        }
        if (__any(cnt >= BUF)) flush();
    }
    flush();
    __syncthreads();                                    // retire scan buffers

    // dump sorted partial lists: point = lane, segment = wave
    float2* dst = smem + lane * 81 + wave * KNB;
#pragma unroll
    for (int j = 0; j < KNB; ++j)
        dst[j] = make_float2(vals[j], __int_as_float(idxs[j]));
    __syncthreads();

    if (wave == 0) {
        const float2* L = smem + lane * 81;
        int p0 = 0, p1 = 0, p2 = 0, p3 = 0;
        int* kout = knn + (size_t)(g0 + lane) * KNB;
#pragma unroll
        for (int k = 0; k < KNB; ++k) {                 // heads never exhaust (k<20)
            float2 e0 = L[p0], e1 = L[20 + p1], e2 = L[40 + p2], e3 = L[60 + p3];
            float bv = e0.x; int bi = __float_as_int(e0.y); int bs = 0;
            if (e1.x > bv) { bv = e1.x; bi = __float_as_int(e1.y); bs = 1; }
            if (e2.x > bv) { bv = e2.x; bi = __float_as_int(e2.y); bs = 2; }
            if (e3.x > bv) { bv = e3.x; bi = __float_as_int(e3.y); bs = 3; }
            kout[k] = bi;
            p0 += (bs == 0); p1 += (bs == 1); p2 += (bs == 2); p3 += (bs == 3);
        }
    }
}

// ---------------------------------------------------------------------------
// Kernel C: fused gather + conv1(6->64)+BN+ReLU + max/mean pool over K +
// conv2(128->64)+BN+ReLU. Wave-per-point-group (lane = output channel).
// Neighbor coords gathered as packed float4 (lanes 0..19), prefetched in
// groups of 8 points to overlap gather latency with compute.
// ---------------------------------------------------------------------------
__global__ __launch_bounds__(256) void fuse_kernel(
    const float4* __restrict__ xp, const int* __restrict__ knn,
    const float* __restrict__ w1, const float* __restrict__ b1,
    const float* __restrict__ g1, const float* __restrict__ be1,
    const float* __restrict__ rm1, const float* __restrict__ rv1,
    const float* __restrict__ w2, const float* __restrict__ b2,
    const float* __restrict__ g2, const float* __restrict__ be2,
    const float* __restrict__ rm2, const float* __restrict__ rv2,
    float* __restrict__ out)
{
    __shared__ float w2s[64 * 129];       // +1 pad -> 2-way bank alias (free)
    __shared__ float buf[64 * 65];        // output staging, padded
    __shared__ float cent[3][64];         // this block's 64 center points

    const int tid  = threadIdx.x;
    const int wave = tid >> 6;
    const int lane = tid & 63;
    const int g0   = blockIdx.x * 64;
    const int b    = g0 >> 12;
    const int n0   = g0 & (NPB - 1);

    for (int i = tid; i < 64 * 128; i += 256) {
        int o = i >> 7, c = i & 127;
        w2s[o * 129 + c] = w2[i];
    }
    if (tid < 64) {
        float4 q = xp[(b << 12) + n0 + tid];
        cent[0][tid] = q.x; cent[1][tid] = q.y; cent[2][tid] = q.z;
    }
    __syncthreads();

    const int o = lane;
    const float w10 = w1[o*6+0], w11 = w1[o*6+1], w12 = w1[o*6+2];
    const float w13 = w1[o*6+3], w14 = w1[o*6+4], w15 = w1[o*6+5];
    const float sc1 = g1[o] * rsqrtf(rv1[o] + 1e-5f);
    const float sh1 = be1[o] - rm1[o] * sc1;
    const float b1o = b1[o];
    const float sc2 = g2[o] * rsqrtf(rv2[o] + 1e-5f);
    const float sh2 = be2[o] - rm2[o] * sc2;
    const float b2o = b2[o];

    float m1r[16], m2r[16], o2r[16];

    // prefetch all 16 neighbor-index vectors (lane k<20 holds neighbor k)
    int myk[16];
#pragma unroll
    for (int j = 0; j < 16; ++j) {
        const int gp = g0 + wave * 16 + j;
        myk[j] = (lane < KNB) ? knn[(size_t)gp * KNB + lane] : 0;
    }

#pragma unroll 1
    for (int grp = 0; grp < 2; ++grp) {
        float4 nb[8];
#pragma unroll
        for (int jj = 0; jj < 8; ++jj) {
            int j = grp * 8 + jj;
            nb[jj] = (lane < KNB) ? xp[(b << 12) + myk[j]]
                                  : make_float4(0.f, 0.f, 0.f, 0.f);
        }
#pragma unroll
        for (int jj = 0; jj < 8; ++jj) {
            int j  = grp * 8 + jj;
            int pl = wave * 16 + j;
            float c0 = cent[0][pl], c1 = cent[1][pl], c2 = cent[2][pl];
            float difx = __fsub_rn(nb[jj].x, c0);
            float dify = __fsub_rn(nb[jj].y, c1);
            float difz = __fsub_rn(nb[jj].z, c2);
            float base = b1o + c0 * w13 + c1 * w14 + c2 * w15;

            float m1 = -INFINITY, sum = 0.0f;
#pragma unroll
            for (int k = 0; k < KNB; ++k) {
                float d0 = rlf(difx, k);
                float d1 = rlf(dify, k);
                float d2 = rlf(difz, k);
                float h  = fmaf(d2, w12, fmaf(d1, w11, fmaf(d0, w10, base)));
                float r  = fmaxf(0.0f, fmaf(h, sc1, sh1));
                m1  = fmaxf(m1, r);
                sum += r;
            }
            m1r[j] = m1;
            m2r[j] = sum / 20.0f;
        }
    }

    // conv2: c-outer so w2s is read once per c (not once per point)
#pragma unroll
    for (int j = 0; j < 16; ++j) o2r[j] = b2o;
    for (int c = 0; c < 64; ++c) {
        float wa = w2s[o * 129 + c];
        float wb = w2s[o * 129 + 64 + c];
#pragma unroll
        for (int j = 0; j < 16; ++j) {
            o2r[j] = fmaf(rlf(m1r[j], c), wa, o2r[j]);
            o2r[j] = fmaf(rlf(m2r[j], c), wb, o2r[j]);
        }
    }
#pragma unroll
    for (int j = 0; j < 16; ++j)
        o2r[j] = fmaxf(0.0f, fmaf(o2r[j], sc2, sh2));

    const size_t SEC = (size_t)NB * 64 * NPB;   // elements per output section

    // section 1: m1o
#pragma unroll
    for (int j = 0; j < 16; ++j) buf[o * 65 + wave * 16 + j] = m1r[j];
    __syncthreads();
    {
        float* dst = out + SEC;
        for (int r = 0; r < 16; ++r) {
            int oo = r * 4 + wave;
            dst[((size_t)b * 64 + oo) * NPB + n0 + lane] = buf[oo * 65 + lane];
        }
    }
    __syncthreads();

    // section 2: m2o
#pragma unroll
    for (int j = 0; j < 16; ++j) buf[o * 65 + wave * 16 + j] = m2r[j];
    __syncthreads();
    {
        float* dst = out + 2 * SEC;
        for (int r = 0; r < 16; ++r) {
            int oo = r * 4 + wave;
            dst[((size_t)b * 64 + oo) * NPB + n0 + lane] = buf[oo * 65 + lane];
        }
    }
    __syncthreads();

    // section 0: out
#pragma unroll
    for (int j = 0; j < 16; ++j) buf[o * 65 + wave * 16 + j] = o2r[j];
    __syncthreads();
    {
        float* dst = out;
        for (int r = 0; r < 16; ++r) {
            int oo = r * 4 + wave;
            dst[((size_t)b * 64 + oo) * NPB + n0 + lane] = buf[oo * 65 + lane];
        }
    }
}

extern "C" void kernel_launch(void* const* d_in, const int* in_sizes, int n_in,
                              void* d_out, int out_size, void* d_ws, size_t ws_size,
                              hipStream_t stream) {
    const float* x   = (const float*)d_in[0];
    const float* w1  = (const float*)d_in[1];
    const float* b1  = (const float*)d_in[2];
    const float* g1  = (const float*)d_in[3];
    const float* be1 = (const float*)d_in[4];
    const float* rm1 = (const float*)d_in[5];
    const float* rv1 = (const float*)d_in[6];
    const float* w2  = (const float*)d_in[7];
    const float* b2  = (const float*)d_in[8];
    const float* g2  = (const float*)d_in[9];
    const float* be2 = (const float*)d_in[10];
    const float* rm2 = (const float*)d_in[11];
    const float* rv2 = (const float*)d_in[12];

    int*    knn = (int*)d_ws;                               // 2.62 MB
    float4* xp  = (float4*)((char*)d_ws + (size_t)NB * NPB * KNB * 4);  // 512 KB

    pack_kernel<<<(NB * NPB) / 256, 256, 0, stream>>>(x, xp);
    knn_kernel<<<(NB * NPB) / 64, 256, 0, stream>>>(xp, knn);
    fuse_kernel<<<(NB * NPB) / 64, 256, 0, stream>>>(
        xp, knn, w1, b1, g1, be1, rm1, rv1, w2, b2, g2, be2, rm2, rv2,
        (float*)d_out);
}

// Round 4
// 344.415 us; speedup vs baseline: 4.2194x; 1.1033x over previous
//
#include <hip/hip_runtime.h>
#include <cstddef>

#define NPB  4096            // points per batch
#define KNB  20              // neighbors
#define NB   8               // batches
#define NPTS (NB * NPB)      // 32768 total points
#define SEGS 8               // candidate segments per batch
#define SEGSZ 512            // candidates per segment

// ---------------------------------------------------------------------------
// Kernel A: pack (x,y,z,xx) per point into float4 (512 KB, L2-resident).
// xx arithmetic identical to reference numpy fp32 (no FMA, sequential order).
// ---------------------------------------------------------------------------
__global__ __launch_bounds__(256) void pack_kernel(const float* __restrict__ x,
                                                   float4* __restrict__ xp) {
    const int g = blockIdx.x * 256 + threadIdx.x;
    const int b = g >> 12, n = g & (NPB - 1);
    const float* xb = x + (size_t)b * 3 * NPB;
    float a0 = xb[n], a1 = xb[NPB + n], a2 = xb[2 * NPB + n];
    float xx = __fadd_rn(__fadd_rn(__fmul_rn(a0, a0), __fmul_rn(a1, a1)),
                         __fmul_rn(a2, a2));
    xp[g] = make_float4(a0, a1, a2, xx);
}

// ---------------------------------------------------------------------------
// Kernel P: fold BN into conv weights once (global scratch, L1/L2-resident).
// w1f[c][8] = {sc1*w1[c][0..5], sc1*b1[c]+sh1, 0}; w2f[c][o] = sc2[o]*w2[o][c];
// w2b[o] = sc2*b2[o]+sh2[o].
// ---------------------------------------------------------------------------
__global__ __launch_bounds__(256) void prep_kernel(
    const float* __restrict__ w1, const float* __restrict__ b1,
    const float* __restrict__ g1, const float* __restrict__ be1,
    const float* __restrict__ rm1, const float* __restrict__ rv1,
    const float* __restrict__ w2, const float* __restrict__ b2,
    const float* __restrict__ g2, const float* __restrict__ be2,
    const float* __restrict__ rm2, const float* __restrict__ rv2,
    float* __restrict__ w1f, float* __restrict__ w2f, float* __restrict__ w2b)
{
    const int tid = threadIdx.x;
    if (tid < 64) {
        float sc1 = g1[tid] * rsqrtf(rv1[tid] + 1e-5f);
        float sh1 = be1[tid] - rm1[tid] * sc1;
#pragma unroll
        for (int j = 0; j < 6; ++j) w1f[tid * 8 + j] = sc1 * w1[tid * 6 + j];
        w1f[tid * 8 + 6] = sc1 * b1[tid] + sh1;
        w1f[tid * 8 + 7] = 0.f;
        float sc2 = g2[tid] * rsqrtf(rv2[tid] + 1e-5f);
        w2b[tid] = sc2 * b2[tid] + (be2[tid] - rm2[tid] * sc2);
    }
    for (int i = tid; i < 64 * 128; i += 256) {
        int c = i >> 6, o = i & 63;
        float sc2 = g2[o] * rsqrtf(rv2[o] + 1e-5f);
        w2f[i] = sc2 * w2[o * 128 + c];
    }
}

// ---------------------------------------------------------------------------
// Kernel B1: segmented exact top-20 scan. Grid = 512 groups x 2 halves.
// Block = 256 thr = 4 waves; wave = one 512-candidate segment, lane = point.
// Buffered batch-insert (check every 4 candidates, flush at cnt>=12, cap 16).
// Intra-block 4-way merge -> sorted partial 20-list per (point, half) to
// global scratch. Strict '>' + lower-segment-first = lower-index tie
// preference (matches jax.lax.top_k).
// ---------------------------------------------------------------------------
__global__ __launch_bounds__(256) void knn_scan(const float4* __restrict__ xp,
                                                float2* __restrict__ part) {
    __shared__ float2 smem[5120];   // 40KB union: bufs[16][256] / lists[4][20][64]

    const int tid  = threadIdx.x;
    const int wave = tid >> 6, lane = tid & 63;
    const int grp  = blockIdx.x >> 1, half = blockIdx.x & 1;
    const int g0   = grp * 64;
    const int b    = g0 >> 12;
    const int seg  = half * 4 + wave;

    const float4 me = xp[g0 + lane];                 // coalesced
    const float cx = me.x, cy = me.y, cz = me.z, xxn = me.w;

    float vals[KNB];
    int   idxs[KNB];
#pragma unroll
    for (int j = 0; j < KNB; ++j) { vals[j] = -INFINITY; idxs[j] = 0; }
    float vmin = -INFINITY;
    int   cnt  = 0;

    auto flush = [&]() {
#pragma unroll
        for (int j = 0; j < 16; ++j) {
            bool act = (j < cnt);
            if (!__any(act)) break;
            float2 e = smem[j * 256 + tid];
            float cv = act ? e.x : -INFINITY;
            int   ci = __float_as_int(e.y);
            if (__any(cv > vmin)) {
#pragma unroll
                for (int jj = 0; jj < KNB; ++jj) {
                    bool gt = cv > vals[jj];
                    float tv = vals[jj]; int ti = idxs[jj];
                    vals[jj] = gt ? cv : tv;  idxs[jj] = gt ? ci : ti;
                    cv       = gt ? tv : cv;  ci       = gt ? ti : ci;
                }
                vmin = vals[KNB - 1];
            }
        }
        cnt = 0;
    };

    const float4* cand  = xp + (b << 12) + seg * SEGSZ;
    const int     ibase = seg * SEGSZ;
#pragma unroll 1
    for (int i = 0; i < SEGSZ; i += 4) {
#pragma unroll
        for (int u = 0; u < 4; ++u) {
            float4 q = cand[i + u];                  // wave-uniform 16B load
            float inner = __fadd_rn(__fadd_rn(__fmul_rn(cx, q.x), __fmul_rn(cy, q.y)),
                                    __fmul_rn(cz, q.z));
            float d = __fsub_rn(__fsub_rn(__fmul_rn(2.0f, inner), xxn), q.w);
            if (d > vmin) {
                smem[cnt * 256 + tid] = make_float2(d, __int_as_float(ibase + i + u));
                ++cnt;
            }
        }
        if (__any(cnt >= 12)) flush();               // cap: 11 + 4 = 15 <= 16
    }
    flush();
    __syncthreads();                                 // retire scan buffers

    // dump sorted partial lists transposed: lists[seg][j][pt] (conflict-free)
#pragma unroll
    for (int j = 0; j < KNB; ++j)
        smem[(wave * KNB + j) * 64 + lane] = make_float2(vals[j], __int_as_float(idxs[j]));
    __syncthreads();

    if (wave == 0) {
        int p0 = 0, p1 = 0, p2 = 0, p3 = 0;
        float2* dst = part + ((size_t)half * NPTS + g0 + lane) * KNB;
#pragma unroll
        for (int k = 0; k < KNB; ++k) {              // heads never exhaust (k<20)
            float2 e0 = smem[(0 * KNB + p0) * 64 + lane];
            float2 e1 = smem[(1 * KNB + p1) * 64 + lane];
            float2 e2 = smem[(2 * KNB + p2) * 64 + lane];
            float2 e3 = smem[(3 * KNB + p3) * 64 + lane];
            float bv = e0.x; float bi = e0.y; int bs = 0;
            if (e1.x > bv) { bv = e1.x; bi = e1.y; bs = 1; }
            if (e2.x > bv) { bv = e2.x; bi = e2.y; bs = 2; }
            if (e3.x > bv) { bv = e3.x; bi = e3.y; bs = 3; }
            dst[k] = make_float2(bv, bi);
            p0 += (bs == 0); p1 += (bs == 1); p2 += (bs == 2); p3 += (bs == 3);
        }
    }
}

// ---------------------------------------------------------------------------
// Kernel B2: final 2-way merge of the half-lists; writes transposed
// knn_t[k][point] for coalesced fuse reads. Tie -> half0 (lower index).
// ---------------------------------------------------------------------------
__global__ __launch_bounds__(256) void knn_merge(const float2* __restrict__ part,
                                                 int* __restrict__ knn_t) {
    const int p = blockIdx.x * 256 + threadIdx.x;
    const float2* A = part + (size_t)p * KNB;
    const float2* B = part + ((size_t)NPTS + p) * KNB;
    int pa = 0, pb = 0;
#pragma unroll
    for (int k = 0; k < KNB; ++k) {
        float2 ea = A[pa], eb = B[pb];
        bool t = eb.x > ea.x;
        knn_t[k * NPTS + p] = __float_as_int(t ? eb.y : ea.y);
        pa += !t; pb += t;
    }
}

// ---------------------------------------------------------------------------
// Kernel C: fused gather + conv1+BN+ReLU + max/mean pool + conv2+BN+ReLU.
// Thread = point (lane = pt, all 64 lanes active); wave owns a channel
// quarter. Neighbor difs in 60 registers (no readlane, no cross-lane
// chains); m1/m2 staged in cat[128][64] LDS; folded weights read from
// global (broadcast loads, L1-hot). 32 KB LDS.
// ---------------------------------------------------------------------------
__global__ __launch_bounds__(256) void fuse_kernel(
    const float4* __restrict__ xp, const int* __restrict__ knn_t,
    const float* __restrict__ w1f, const float* __restrict__ w2f,
    const float* __restrict__ w2b, float* __restrict__ out)
{
    __shared__ float cat[128 * 64];   // 32KB: [c][pt], c<64: m1, c>=64: m2

    const int tid  = threadIdx.x;
    const int wave = tid >> 6, lane = tid & 63;
    const int g0   = blockIdx.x * 64;
    const int b    = g0 >> 12, n0 = g0 & (NPB - 1);

    const float4 me = xp[g0 + lane];
    const float c0 = me.x, c1 = me.y, c2 = me.z;

    // gather 20 neighbor difs into registers (coalesced knn_t reads)
    int nidx[KNB];
#pragma unroll
    for (int k = 0; k < KNB; ++k) nidx[k] = knn_t[k * NPTS + g0 + lane];
    float dx[KNB], dy[KNB], dz[KNB];
#pragma unroll
    for (int k = 0; k < KNB; ++k) {
        float4 nb = xp[(b << 12) + nidx[k]];
        dx[k] = __fsub_rn(nb.x, c0);
        dy[k] = __fsub_rn(nb.y, c1);
        dz[k] = __fsub_rn(nb.z, c2);
    }

    // conv1 quarter: channels [16*wave, 16*wave+16)
    const float4* w1fv = (const float4*)w1f;
#pragma unroll 1
    for (int cc = 0; cc < 16; ++cc) {
        int c = wave * 16 + cc;
        float4 wa = w1fv[c * 2];          // {W0,W1,W2,W3}
        float4 wb = w1fv[c * 2 + 1];      // {W4,W5,B1',pad}
        float base = wb.z + wa.w * c0 + wb.x * c1 + wb.y * c2;
        float m1 = -INFINITY, s = 0.f;
#pragma unroll
        for (int k = 0; k < KNB; ++k) {
            float h = fmaf(dz[k], wa.z, fmaf(dy[k], wa.y, fmaf(dx[k], wa.x, base)));
            float r = fmaxf(0.f, h);
            m1 = fmaxf(m1, r);
            s += r;
        }
        cat[c * 64 + lane]        = m1;
        cat[(64 + c) * 64 + lane] = s / 20.0f;
    }
    __syncthreads();

    const size_t SEC = (size_t)NB * 64 * NPB;   // elements per output section

    // write m1/m2 rows straight from cat (coalesced 256B rows)
#pragma unroll 1
    for (int q = 0; q < 32; ++q) {
        int r  = wave * 32 + q;                 // 0..127
        int ch = r & 63;
        float* dst = out + SEC * (1 + (r >> 6)) + ((size_t)b * 64 + ch) * NPB + n0;
        dst[lane] = cat[r * 64 + lane];
    }

    // conv2 quarter: outputs [16*wave, 16*wave+16)
    const int ob = wave * 16;
    float acc[16];
#pragma unroll
    for (int j = 0; j < 16; ++j) acc[j] = w2b[ob + j];
#pragma unroll 1
    for (int c = 0; c < 128; ++c) {
        float v = cat[c * 64 + lane];
        const float4* wr = (const float4*)(w2f + c * 64 + ob);
        float4 q0 = wr[0], q1 = wr[1], q2 = wr[2], q3 = wr[3];
        acc[0]  = fmaf(v, q0.x, acc[0]);  acc[1]  = fmaf(v, q0.y, acc[1]);
        acc[2]  = fmaf(v, q0.z, acc[2]);  acc[3]  = fmaf(v, q0.w, acc[3]);
        acc[4]  = fmaf(v, q1.x, acc[4]);  acc[5]  = fmaf(v, q1.y, acc[5]);
        acc[6]  = fmaf(v, q1.z, acc[6]);  acc[7]  = fmaf(v, q1.w, acc[7]);
        acc[8]  = fmaf(v, q2.x, acc[8]);  acc[9]  = fmaf(v, q2.y, acc[9]);
        acc[10] = fmaf(v, q2.z, acc[10]); acc[11] = fmaf(v, q2.w, acc[11]);
        acc[12] = fmaf(v, q3.x, acc[12]); acc[13] = fmaf(v, q3.y, acc[13]);
        acc[14] = fmaf(v, q3.z, acc[14]); acc[15] = fmaf(v, q3.w, acc[15]);
    }
#pragma unroll
    for (int j = 0; j < 16; ++j) acc[j] = fmaxf(0.f, acc[j]);

    __syncthreads();                            // all waves done reading cat
#pragma unroll
    for (int j = 0; j < 16; ++j) cat[(ob + j) * 64 + lane] = acc[j];
    __syncthreads();
#pragma unroll 1
    for (int q = 0; q < 16; ++q) {
        int oo = wave * 16 + q;
        out[((size_t)b * 64 + oo) * NPB + n0 + lane] = cat[oo * 64 + lane];
    }
}

extern "C" void kernel_launch(void* const* d_in, const int* in_sizes, int n_in,
                              void* d_out, int out_size, void* d_ws, size_t ws_size,
                              hipStream_t stream) {
    const float* x   = (const float*)d_in[0];
    const float* w1  = (const float*)d_in[1];
    const float* b1  = (const float*)d_in[2];
    const float* g1  = (const float*)d_in[3];
    const float* be1 = (const float*)d_in[4];
    const float* rm1 = (const float*)d_in[5];
    const float* rv1 = (const float*)d_in[6];
    const float* w2  = (const float*)d_in[7];
    const float* b2  = (const float*)d_in[8];
    const float* g2  = (const float*)d_in[9];
    const float* be2 = (const float*)d_in[10];
    const float* rm2 = (const float*)d_in[11];
    const float* rv2 = (const float*)d_in[12];

    char*   ws    = (char*)d_ws;
    float4* xp    = (float4*)ws;                                // 512 KB
    int*    knn_t = (int*)(ws + 512 * 1024);                    // 2.62 MB
    float*  w1f   = (float*)(ws + 512 * 1024 + (size_t)KNB * NPTS * 4);
    float*  w2f   = w1f + 64 * 8;
    float*  w2b   = w2f + 64 * 128;
    // partial lists aliased into d_out (10.5 MB); fuse overwrites d_out after
    float2* part  = (float2*)d_out;

    pack_kernel<<<NPTS / 256, 256, 0, stream>>>(x, xp);
    prep_kernel<<<1, 256, 0, stream>>>(w1, b1, g1, be1, rm1, rv1,
                                       w2, b2, g2, be2, rm2, rv2, w1f, w2f, w2b);
    knn_scan<<<1024, 256, 0, stream>>>(xp, part);
    knn_merge<<<NPTS / 256, 256, 0, stream>>>(part, knn_t);
    fuse_kernel<<<NPTS / 64, 256, 0, stream>>>(xp, knn_t, w1f, w2f, w2b,
                                               (float*)d_out);
}